// Round 1
// baseline (2998.078 us; speedup 1.0000x reference)
//
#include <hip/hip_runtime.h>

// VGG16-A spiking NN, multi-compartment LIF (K=2), T=3, B=4, fp32.
// Round 7:
//  - conv_mid: 4-deep software pipeline (v0..v3 rotation, static indexing)
//    to hide ~200-400cy gathered-load latency behind 3 FMA phases.
//  - conv_mid occupancy: L1-L3 NW=8 (512thr), L4-L6 NW=16 (1024thr) ->
//    4096 waves (16/CU) instead of 2048 (8/CU). __launch_bounds__(.,4)
//    caps VGPR at 128 to guarantee it.
//  - L0: conv(x,w0) is timestep-invariant -> computed once at t=0 into
//    syn0 ws buffer, reloaded at t=1,2.

#define BATCH 4

__device__ __forceinline__ float lif_update(float mem_in, float syn, float thr,
                                            float leak, float* mem_out) {
    float m = leak * mem_in + syn;
    float val = 0.f;
    if ((m / thr - 1.f > 0.f) && (1.f - m / (2.f * thr) >= 0.f)) val += 1.f;
    if ((m / (2.f * thr) - 1.f > 0.f) && (1.f - m / (4.f * thr) >= 0.f)) val += 2.f;
    *mem_out = m - thr * val;
    return val;
}

// Element-per-thread conv+LIF (layer 0 only, IC=3). Conv result is
// timestep-invariant (analog input encoding): computed at t=0 into syn0,
// reloaded afterwards.
__global__ void conv_lif_kernel(const float* __restrict__ in,
                                const float* __restrict__ w,
                                float* __restrict__ syn0,
                                float* __restrict__ mem,
                                float* __restrict__ out,
                                const float* __restrict__ thr_v,
                                const float* __restrict__ leak_v,
                                int layer, int IC, int OC, int H, int W, int n,
                                int first) {
    int idx = blockIdx.x * blockDim.x + threadIdx.x;
    if (idx >= n) return;

    float syn;
    if (first) {
        int x  = idx % W;
        int y  = (idx / W) % H;
        int oc = (idx / (W * H)) % OC;
        int b  = idx / (W * H * OC);

        const float* wp = w + (size_t)oc * IC * 9;
        const float* ip = in + (size_t)b * IC * H * W;

        syn = 0.f;
        for (int ic = 0; ic < IC; ++ic) {
            const float* ipc = ip + (size_t)ic * H * W;
            const float* wpc = wp + ic * 9;
#pragma unroll
            for (int ky = 0; ky < 3; ++ky) {
                int yy = y + ky - 1;
                if (yy < 0 || yy >= H) continue;
#pragma unroll
                for (int kx = 0; kx < 3; ++kx) {
                    int xx = x + kx - 1;
                    if (xx < 0 || xx >= W) continue;
                    syn = fmaf(ipc[yy * W + xx], wpc[ky * 3 + kx], syn);
                }
            }
        }
        syn0[idx] = syn;
    } else {
        syn = syn0[idx];
    }
    float mi = first ? 0.f : mem[idx];
    float mo;
    float val = lif_update(mi, syn, thr_v[layer], leak_v[layer], &mo);
    mem[idx] = mo;
    out[idx] = val;
}

// ---- conv_mid helpers: statically-indexed pipeline stages ----
__device__ __forceinline__ void mid_load(float v[9], const float* __restrict__ ip,
                                         const int off[9], const bool msk[9]) {
#pragma unroll
    for (int k = 0; k < 9; ++k) v[k] = msk[k] ? ip[off[k]] : 0.f;
}

template <int OCT>
__device__ __forceinline__ void mid_fma(const float v[9], const float* __restrict__ wp,
                                        int IC, float acc[OCT]) {
#pragma unroll
    for (int t = 0; t < OCT; ++t) {
        const float* wt = wp + (size_t)t * IC * 9;
#pragma unroll
        for (int k = 0; k < 9; ++k) acc[t] = fmaf(v[k], wt[k], acc[t]);
    }
}

// Layers 1-6. Block = NW waves. blockIdx -> (b, pixel-chunk, oc-group).
// Lane = pixel within 64-pixel chunk. Wave wv accumulates over its IC/NW
// channel chunk into acc[OCT] with a 4-deep software pipeline; LDS reduce
// across waves; LIF; optional fused 2x2 avg-pool writing pooled out.
// Requires (IC/NW) % 4 == 0.
template <int OCT, int NW, int POOL>
__global__ __launch_bounds__(NW * 64, 4)
void conv_mid_kernel(const float* __restrict__ in,
                     const float* __restrict__ w,
                     float* __restrict__ mem,
                     float* __restrict__ out,
                     const float* __restrict__ thr_v,
                     const float* __restrict__ leak_v,
                     int layer, int IC, int OC, int H, int W,
                     int first) {
    int tid = threadIdx.x;
    int lane = tid & 63;
    int wv = tid >> 6;  // 0..NW-1
    int ocg = OC / OCT;
    int HW = H * W;
    int chunks = HW >> 6;
    int bid = blockIdx.x;
    int g  = bid % ocg;
    int ch = (bid / ocg) % chunks;
    int b  = bid / (ocg * chunks);
    int rpw = 64 / W;
    int y = ch * rpw + lane / W;
    int x = lane % W;
    int oc0 = g * OCT;

    int off[9];
    bool msk[9];
#pragma unroll
    for (int ky = 0; ky < 3; ++ky)
#pragma unroll
        for (int kx = 0; kx < 3; ++kx) {
            int yy = y + ky - 1, xx = x + kx - 1;
            bool v = (yy >= 0 && yy < H && xx >= 0 && xx < W);
            msk[ky * 3 + kx] = v;
            off[ky * 3 + kx] = v ? yy * W + xx : 0;
        }

    float acc[OCT];
#pragma unroll
    for (int t = 0; t < OCT; ++t) acc[t] = 0.f;

    const float* ibase = in + (size_t)b * IC * HW;
    const float* wbase = w + (size_t)oc0 * IC * 9;

    int icpw = IC / NW;
    int ic0 = wv * icpw;
    int icend = ic0 + icpw;

    // 4-deep software pipeline: v0..v3 hold ics ic..ic+3; each phase's
    // reload targets ic+4..ic+7, consumed 3 FMA phases later.
    float v0[9], v1[9], v2[9], v3[9];
    mid_load(v0, ibase + (size_t)(ic0 + 0) * HW, off, msk);
    mid_load(v1, ibase + (size_t)(ic0 + 1) * HW, off, msk);
    mid_load(v2, ibase + (size_t)(ic0 + 2) * HW, off, msk);
    mid_load(v3, ibase + (size_t)(ic0 + 3) * HW, off, msk);

    int ic = ic0;
    for (; ic + 4 < icend; ic += 4) {
        mid_fma<OCT>(v0, wbase + (size_t)(ic + 0) * 9, IC, acc);
        mid_load(v0, ibase + (size_t)(ic + 4) * HW, off, msk);
        mid_fma<OCT>(v1, wbase + (size_t)(ic + 1) * 9, IC, acc);
        mid_load(v1, ibase + (size_t)(ic + 5) * HW, off, msk);
        mid_fma<OCT>(v2, wbase + (size_t)(ic + 2) * 9, IC, acc);
        mid_load(v2, ibase + (size_t)(ic + 6) * HW, off, msk);
        mid_fma<OCT>(v3, wbase + (size_t)(ic + 3) * 9, IC, acc);
        mid_load(v3, ibase + (size_t)(ic + 7) * HW, off, msk);
    }
    // tail: last 4 ics, no prefetch
    mid_fma<OCT>(v0, wbase + (size_t)(ic + 0) * 9, IC, acc);
    mid_fma<OCT>(v1, wbase + (size_t)(ic + 1) * 9, IC, acc);
    mid_fma<OCT>(v2, wbase + (size_t)(ic + 2) * 9, IC, acc);
    mid_fma<OCT>(v3, wbase + (size_t)(ic + 3) * 9, IC, acc);

    __shared__ float red[NW][OCT][64];
#pragma unroll
    for (int t = 0; t < OCT; ++t) red[wv][t][lane] = acc[t];
    __syncthreads();

    __shared__ float vals[OCT][64];
    float thr = thr_v[layer], leak = leak_v[layer];
    for (int s = tid; s < OCT * 64; s += NW * 64) {
        int t = s >> 6, p = s & 63;
        float sum = 0.f;
#pragma unroll
        for (int q = 0; q < NW; ++q) sum += red[q][t][p];
        size_t idx = (size_t)(b * OC + oc0 + t) * HW + ch * 64 + p;
        float mi = first ? 0.f : mem[idx];
        float mo;
        float val = lif_update(mi, sum, thr, leak, &mo);
        mem[idx] = mo;
        if (POOL) vals[t][p] = val;
        else out[idx] = val;
    }
    if (POOL) {
        __syncthreads();
        int Wo = W >> 1, Ho = H >> 1;
        for (int s = tid; s < OCT * 16; s += NW * 64) {
            int t = s >> 4, q = s & 15;
            int pr = q / Wo, pc = q % Wo;
            float pv = 0.25f * (vals[t][(2 * pr) * W + 2 * pc] +
                                vals[t][(2 * pr) * W + 2 * pc + 1] +
                                vals[t][(2 * pr + 1) * W + 2 * pc] +
                                vals[t][(2 * pr + 1) * W + 2 * pc + 1]);
            size_t pidx = ((size_t)(b * OC + oc0 + t) * Ho +
                           (ch * (rpw >> 1) + pr)) * Wo + pc;
            out[pidx] = pv;
        }
    }
}

// Layers 7-12 (4x4 / 2x2 planes). Block = 4 waves, one oc per block.
// ic = lane + 64*wv (+256*pass). Per-wave butterfly transpose-reduce;
// LDS [4][M] cross-wave reduce; parallel LIF; optional fused pool.
template <int S, int POOL>
__global__ void conv_small4_kernel(const float* __restrict__ in,
                                   const float* __restrict__ w,
                                   float* __restrict__ mem,
                                   float* __restrict__ out,
                                   const float* __restrict__ thr_v,
                                   const float* __restrict__ leak_v,
                                   int layer, int IC, int OC, int first) {
    constexpr int SS = S * S;
    constexpr int M = 4 * SS;              // 64 (S=4) or 16 (S=2)
    constexpr int LOG2M = (S == 4) ? 6 : 4;
    int tid = threadIdx.x;
    int lane = tid & 63;
    int wv = tid >> 6;  // 0..3
    int oc = blockIdx.x;

    float acc[M];
#pragma unroll
    for (int i = 0; i < M; ++i) acc[i] = 0.f;

    const float* wrow = w + (size_t)oc * IC * 9;
    for (int ic = lane + (wv << 6); ic < IC; ic += 256) {
        const float* wp = wrow + (size_t)ic * 9;
        float wvv[9];
#pragma unroll
        for (int k = 0; k < 9; ++k) wvv[k] = wp[k];
#pragma unroll
        for (int b = 0; b < 4; ++b) {
            const float4* ip = (const float4*)(in + (size_t)(b * IC + ic) * SS);
            float pv[SS];
#pragma unroll
            for (int q = 0; q < SS / 4; ++q) {
                float4 t4 = ip[q];
                pv[4 * q + 0] = t4.x;
                pv[4 * q + 1] = t4.y;
                pv[4 * q + 2] = t4.z;
                pv[4 * q + 3] = t4.w;
            }
#pragma unroll
            for (int y = 0; y < S; ++y)
#pragma unroll
                for (int x = 0; x < S; ++x) {
                    float a = acc[b * SS + y * S + x];
#pragma unroll
                    for (int ky = 0; ky < 3; ++ky) {
                        int yy = y + ky - 1;
                        if (yy < 0 || yy >= S) continue;
#pragma unroll
                        for (int kx = 0; kx < 3; ++kx) {
                            int xx = x + kx - 1;
                            if (xx < 0 || xx >= S) continue;
                            a = fmaf(pv[yy * S + xx], wvv[ky * 3 + kx], a);
                        }
                    }
                    acc[b * SS + y * S + x] = a;
                }
        }
    }

    // per-wave transpose-reduce: M accs across 64 lanes -> 1 value per lane
#pragma unroll
    for (int step = 0; step < LOG2M; ++step) {
        const int offx = 1 << step;
        const int half = M >> (step + 1);
        const bool hi = (lane & offx) != 0;
#pragma unroll
        for (int i = 0; i < half; ++i) {
            float sent = hi ? acc[i] : acc[i + half];
            float got = __shfl_xor(sent, offx);
            acc[i] = (hi ? acc[i + half] : acc[i]) + got;
        }
    }
    float sum = acc[0];
#pragma unroll
    for (int offx = M; offx < 64; offx <<= 1) sum += __shfl_xor(sum, offx);

    __shared__ float red[4][M];
    int o = (int)(__brev((unsigned)(lane & (M - 1))) >> (32 - LOG2M));
    if (lane < M) red[wv][o] = sum;
    __syncthreads();

    __shared__ float pvs[M];
    if (tid < M) {
        float tot = red[0][tid] + red[1][tid] + red[2][tid] + red[3][tid];
        int b = tid / SS, p = tid % SS;
        size_t idx = (size_t)(b * OC + oc) * SS + p;
        float mi = first ? 0.f : mem[idx];
        float mo;
        float val = lif_update(mi, tot, thr_v[layer], leak_v[layer], &mo);
        mem[idx] = mo;
        if (POOL) pvs[tid] = val;
        else out[idx] = val;
    }
    if (POOL) {
        __syncthreads();
        constexpr int Sh = S / 2, SSh = Sh * Sh;
        if (tid < 4 * SSh) {
            int b = tid / SSh, q = tid % SSh;
            int pr = q / Sh, pc = q % Sh;
            float pv = 0.25f * (pvs[b * SS + (2 * pr) * S + 2 * pc] +
                                pvs[b * SS + (2 * pr) * S + 2 * pc + 1] +
                                pvs[b * SS + (2 * pr + 1) * S + 2 * pc] +
                                pvs[b * SS + (2 * pr + 1) * S + 2 * pc + 1]);
            out[((size_t)(b * OC + oc) * Sh + pr) * Sh + pc] = pv;
        }
    }
}

// Wave-per-output-neuron FC+LIF (float4 K-split, 4-batch reuse).
__global__ void fc_lif_wave_kernel(const float* __restrict__ in,
                                   const float* __restrict__ w,
                                   float* __restrict__ mem,
                                   float* __restrict__ out,
                                   const float* __restrict__ thr_v,
                                   const float* __restrict__ leak_v,
                                   int layer, int Kd, int N, int first) {
    int wave = (blockIdx.x * blockDim.x + threadIdx.x) >> 6;
    int lane = threadIdx.x & 63;
    if (wave >= N) return;
    int j = wave;
    int K4 = Kd >> 2;
    const float4* wp = (const float4*)(w + (size_t)j * Kd);
    const float4* ip = (const float4*)in;
    float a0 = 0.f, a1 = 0.f, a2 = 0.f, a3 = 0.f;
    for (int k = lane; k < K4; k += 64) {
        float4 wv = wp[k];
        float4 v0 = ip[k];
        float4 v1 = ip[K4 + k];
        float4 v2 = ip[2 * K4 + k];
        float4 v3 = ip[3 * K4 + k];
        a0 = fmaf(wv.x, v0.x, fmaf(wv.y, v0.y, fmaf(wv.z, v0.z, fmaf(wv.w, v0.w, a0))));
        a1 = fmaf(wv.x, v1.x, fmaf(wv.y, v1.y, fmaf(wv.z, v1.z, fmaf(wv.w, v1.w, a1))));
        a2 = fmaf(wv.x, v2.x, fmaf(wv.y, v2.y, fmaf(wv.z, v2.z, fmaf(wv.w, v2.w, a2))));
        a3 = fmaf(wv.x, v3.x, fmaf(wv.y, v3.y, fmaf(wv.z, v3.z, fmaf(wv.w, v3.w, a3))));
    }
#pragma unroll
    for (int off = 32; off > 0; off >>= 1) {
        a0 += __shfl_xor(a0, off);
        a1 += __shfl_xor(a1, off);
        a2 += __shfl_xor(a2, off);
        a3 += __shfl_xor(a3, off);
    }
    if (lane == 0) {
        float thr = thr_v[layer], leak = leak_v[layer];
        float accv[4] = {a0, a1, a2, a3};
#pragma unroll
        for (int b = 0; b < BATCH; ++b) {
            float mi = first ? 0.f : mem[(size_t)b * N + j];
            float mo;
            float val = lif_update(mi, accv[b], thr, leak, &mo);
            mem[(size_t)b * N + j] = mo;
            out[(size_t)b * N + j] = val;
        }
    }
}

// One 64-thread block per (b, label). logits (+)= in[b,:] . w[l,:]
__global__ void fc2_acc_kernel(const float* __restrict__ in,
                               const float* __restrict__ w,
                               float* __restrict__ logits,
                               int Kd, int L, int init) {
    int o = blockIdx.x;
    int l = o % L;
    int b = o / L;
    int K4 = Kd >> 2;
    const float4* ip = (const float4*)(in + (size_t)b * Kd);
    const float4* wp = (const float4*)(w + (size_t)l * Kd);
    float s = 0.f;
    for (int k = threadIdx.x; k < K4; k += 64) {
        float4 iv = ip[k];
        float4 wv = wp[k];
        s = fmaf(iv.x, wv.x, fmaf(iv.y, wv.y, fmaf(iv.z, wv.z, fmaf(iv.w, wv.w, s))));
    }
#pragma unroll
    for (int off = 32; off > 0; off >>= 1) s += __shfl_xor(s, off);
    if (threadIdx.x == 0) logits[o] = init ? s : logits[o] + s;
}

extern "C" void kernel_launch(void* const* d_in, const int* in_sizes, int n_in,
                              void* d_out, int out_size, void* d_ws, size_t ws_size,
                              hipStream_t stream) {
    const float* x = (const float*)d_in[0];
    const float* convw[13];
    for (int i = 0; i < 13; ++i) convw[i] = (const float*)d_in[1 + i];
    const float* fc0 = (const float*)d_in[14];
    const float* fc1 = (const float*)d_in[15];
    const float* fc2 = (const float*)d_in[16];
    const float* thr = (const float*)d_in[17];
    const float* leak = (const float*)d_in[18];

    static const int IC[13] = {3, 64, 64, 128, 128, 256, 256, 256, 512, 512, 512, 512, 512};
    static const int OC[13] = {64, 64, 128, 128, 256, 256, 256, 512, 512, 512, 512, 512, 512};
    static const int HH[13] = {32, 32, 16, 16, 8, 8, 8, 4, 4, 4, 2, 2, 2};

    float* ws = (float*)d_ws;
    size_t off = 0;
    float* convmem[13];
    for (int i = 0; i < 13; ++i) {
        convmem[i] = ws + off;
        off += (size_t)BATCH * OC[i] * HH[i] * HH[i];
    }
    float* mfc0 = ws + off; off += BATCH * 4096;
    float* mfc1 = ws + off; off += BATCH * 4096;
    float* syn0 = ws + off; off += (size_t)BATCH * 64 * 32 * 32;  // L0 conv cache
    float* bufs[3];
    for (int i = 0; i < 3; ++i) { bufs[i] = ws + off; off += 262144; }

    for (int t = 0; t < 3; ++t) {
        int first = (t == 0);
        const float* src = x;
        int cur = -1;
        for (int i = 0; i < 13; ++i) {
            int d = (cur + 1) % 3;
            if (cur < 0) d = 0;
            int H = HH[i], W = HH[i];
            if (i == 0) {
                int n = BATCH * OC[i] * H * W;
                conv_lif_kernel<<<(n + 255) / 256, 256, 0, stream>>>(
                    src, convw[i], syn0, convmem[i], bufs[d], thr, leak, i,
                    IC[i], OC[i], H, W, n, first);
            } else if (i == 1) {
                // 64->64 @32x32, pool: OCT=8, NW=8 (icpw=8)
                int blocks = BATCH * (H * W / 64) * (OC[i] / 8);
                conv_mid_kernel<8, 8, 1><<<blocks, 512, 0, stream>>>(
                    src, convw[i], convmem[i], bufs[d], thr, leak, i,
                    IC[i], OC[i], H, W, first);
            } else if (i == 2) {
                // 64->128 @16x16: OCT=4, NW=8 (icpw=8)
                int blocks = BATCH * (H * W / 64) * (OC[i] / 4);
                conv_mid_kernel<4, 8, 0><<<blocks, 512, 0, stream>>>(
                    src, convw[i], convmem[i], bufs[d], thr, leak, i,
                    IC[i], OC[i], H, W, first);
            } else if (i == 3) {
                // 128->128 @16x16, pool: OCT=4, NW=8 (icpw=16)
                int blocks = BATCH * (H * W / 64) * (OC[i] / 4);
                conv_mid_kernel<4, 8, 1><<<blocks, 512, 0, stream>>>(
                    src, convw[i], convmem[i], bufs[d], thr, leak, i,
                    IC[i], OC[i], H, W, first);
            } else if (i == 4 || i == 5) {
                // @8x8: OCT=4, NW=16 (1024thr; icpw=8/16) -> 4096 waves
                int blocks = BATCH * (H * W / 64) * (OC[i] / 4);
                conv_mid_kernel<4, 16, 0><<<blocks, 1024, 0, stream>>>(
                    src, convw[i], convmem[i], bufs[d], thr, leak, i,
                    IC[i], OC[i], H, W, first);
            } else if (i == 6) {
                int blocks = BATCH * (H * W / 64) * (OC[i] / 4);
                conv_mid_kernel<4, 16, 1><<<blocks, 1024, 0, stream>>>(
                    src, convw[i], convmem[i], bufs[d], thr, leak, i,
                    IC[i], OC[i], H, W, first);
            } else if (i == 7 || i == 8) {
                conv_small4_kernel<4, 0><<<OC[i], 256, 0, stream>>>(
                    src, convw[i], convmem[i], bufs[d], thr, leak, i,
                    IC[i], OC[i], first);
            } else if (i == 9) {
                conv_small4_kernel<4, 1><<<OC[i], 256, 0, stream>>>(
                    src, convw[i], convmem[i], bufs[d], thr, leak, i,
                    IC[i], OC[i], first);
            } else {  // 10..12, 2x2
                conv_small4_kernel<2, 0><<<OC[i], 256, 0, stream>>>(
                    src, convw[i], convmem[i], bufs[d], thr, leak, i,
                    IC[i], OC[i], first);
            }
            cur = d; src = bufs[cur];
        }
        {
            int d = (cur + 1) % 3;
            fc_lif_wave_kernel<<<(4096 * 64) / 256, 256, 0, stream>>>(
                src, fc0, mfc0, bufs[d], thr, leak, 13, 2048, 4096, first);
            cur = d; src = bufs[cur];
        }
        {
            int d = (cur + 1) % 3;
            fc_lif_wave_kernel<<<(4096 * 64) / 256, 256, 0, stream>>>(
                src, fc1, mfc1, bufs[d], thr, leak, 14, 4096, 4096, first);
            cur = d; src = bufs[cur];
        }
        fc2_acc_kernel<<<BATCH * 10, 64, 0, stream>>>(
            src, fc2, (float*)d_out, 4096, 10, first);
    }
}

// Round 3
// 1077.667 us; speedup vs baseline: 2.7820x; 2.7820x over previous
//
#include <hip/hip_runtime.h>

// VGG16-A spiking NN, multi-compartment LIF (K=2), T=3, B=4, fp32.
// Round 9 (resubmit of round 8 — bench infra failed twice, no kernel signal):
//  - Round 7's __launch_bounds__(.,4) clamped VGPR to 64 -> the 4-deep
//    pipeline spilled to scratch (400MB WRITE / 300MB FETCH per dispatch,
//    186us). Fix: no min-occupancy clause; let allocator hold the pipeline
//    in registers.
//  - Launch geometry reverted to round-6 known-good (NW=4/8, 256/512 thr).
//  - Kept: 4-deep software pipeline, L0 syn0 timestep-invariant conv cache,
//    fused avg-pool epilogues, first-flag (no memsets).

#define BATCH 4

__device__ __forceinline__ float lif_update(float mem_in, float syn, float thr,
                                            float leak, float* mem_out) {
    float m = leak * mem_in + syn;
    float val = 0.f;
    if ((m / thr - 1.f > 0.f) && (1.f - m / (2.f * thr) >= 0.f)) val += 1.f;
    if ((m / (2.f * thr) - 1.f > 0.f) && (1.f - m / (4.f * thr) >= 0.f)) val += 2.f;
    *mem_out = m - thr * val;
    return val;
}

// Element-per-thread conv+LIF (layer 0 only, IC=3). Conv result is
// timestep-invariant (analog input encoding): computed at t=0 into syn0,
// reloaded afterwards.
__global__ void conv_lif_kernel(const float* __restrict__ in,
                                const float* __restrict__ w,
                                float* __restrict__ syn0,
                                float* __restrict__ mem,
                                float* __restrict__ out,
                                const float* __restrict__ thr_v,
                                const float* __restrict__ leak_v,
                                int layer, int IC, int OC, int H, int W, int n,
                                int first) {
    int idx = blockIdx.x * blockDim.x + threadIdx.x;
    if (idx >= n) return;

    float syn;
    if (first) {
        int x  = idx % W;
        int y  = (idx / W) % H;
        int oc = (idx / (W * H)) % OC;
        int b  = idx / (W * H * OC);

        const float* wp = w + (size_t)oc * IC * 9;
        const float* ip = in + (size_t)b * IC * H * W;

        syn = 0.f;
        for (int ic = 0; ic < IC; ++ic) {
            const float* ipc = ip + (size_t)ic * H * W;
            const float* wpc = wp + ic * 9;
#pragma unroll
            for (int ky = 0; ky < 3; ++ky) {
                int yy = y + ky - 1;
                if (yy < 0 || yy >= H) continue;
#pragma unroll
                for (int kx = 0; kx < 3; ++kx) {
                    int xx = x + kx - 1;
                    if (xx < 0 || xx >= W) continue;
                    syn = fmaf(ipc[yy * W + xx], wpc[ky * 3 + kx], syn);
                }
            }
        }
        syn0[idx] = syn;
    } else {
        syn = syn0[idx];
    }
    float mi = first ? 0.f : mem[idx];
    float mo;
    float val = lif_update(mi, syn, thr_v[layer], leak_v[layer], &mo);
    mem[idx] = mo;
    out[idx] = val;
}

// ---- conv_mid helpers: statically-indexed pipeline stages ----
__device__ __forceinline__ void mid_load(float v[9], const float* __restrict__ ip,
                                         const int off[9], const bool msk[9]) {
#pragma unroll
    for (int k = 0; k < 9; ++k) v[k] = msk[k] ? ip[off[k]] : 0.f;
}

template <int OCT>
__device__ __forceinline__ void mid_fma(const float v[9], const float* __restrict__ wp,
                                        int IC, float acc[OCT]) {
#pragma unroll
    for (int t = 0; t < OCT; ++t) {
        const float* wt = wp + (size_t)t * IC * 9;
#pragma unroll
        for (int k = 0; k < 9; ++k) acc[t] = fmaf(v[k], wt[k], acc[t]);
    }
}

// Layers 1-6. Block = NW waves. blockIdx -> (b, pixel-chunk, oc-group).
// Lane = pixel within 64-pixel chunk. Wave wv accumulates over its IC/NW
// channel chunk into acc[OCT] with a 4-deep software pipeline; LDS reduce
// across waves; LIF; optional fused 2x2 avg-pool writing pooled out.
// Requires (IC/NW) % 4 == 0.
// NOTE: no min-occupancy clause on launch_bounds — round 7 proved that
// clamping VGPR below the pipeline's live state spills 400MB/dispatch.
template <int OCT, int NW, int POOL>
__global__ __launch_bounds__(NW * 64)
void conv_mid_kernel(const float* __restrict__ in,
                     const float* __restrict__ w,
                     float* __restrict__ mem,
                     float* __restrict__ out,
                     const float* __restrict__ thr_v,
                     const float* __restrict__ leak_v,
                     int layer, int IC, int OC, int H, int W,
                     int first) {
    int tid = threadIdx.x;
    int lane = tid & 63;
    int wv = tid >> 6;  // 0..NW-1
    int ocg = OC / OCT;
    int HW = H * W;
    int chunks = HW >> 6;
    int bid = blockIdx.x;
    int g  = bid % ocg;
    int ch = (bid / ocg) % chunks;
    int b  = bid / (ocg * chunks);
    int rpw = 64 / W;
    int y = ch * rpw + lane / W;
    int x = lane % W;
    int oc0 = g * OCT;

    int off[9];
    bool msk[9];
#pragma unroll
    for (int ky = 0; ky < 3; ++ky)
#pragma unroll
        for (int kx = 0; kx < 3; ++kx) {
            int yy = y + ky - 1, xx = x + kx - 1;
            bool v = (yy >= 0 && yy < H && xx >= 0 && xx < W);
            msk[ky * 3 + kx] = v;
            off[ky * 3 + kx] = v ? yy * W + xx : 0;
        }

    float acc[OCT];
#pragma unroll
    for (int t = 0; t < OCT; ++t) acc[t] = 0.f;

    const float* ibase = in + (size_t)b * IC * HW;
    const float* wbase = w + (size_t)oc0 * IC * 9;

    int icpw = IC / NW;
    int ic0 = wv * icpw;
    int icend = ic0 + icpw;

    // 4-deep software pipeline: v0..v3 hold ics ic..ic+3; each phase's
    // reload targets ic+4..ic+7, consumed 3 FMA phases later.
    float v0[9], v1[9], v2[9], v3[9];
    mid_load(v0, ibase + (size_t)(ic0 + 0) * HW, off, msk);
    mid_load(v1, ibase + (size_t)(ic0 + 1) * HW, off, msk);
    mid_load(v2, ibase + (size_t)(ic0 + 2) * HW, off, msk);
    mid_load(v3, ibase + (size_t)(ic0 + 3) * HW, off, msk);

    int ic = ic0;
    for (; ic + 4 < icend; ic += 4) {
        mid_fma<OCT>(v0, wbase + (size_t)(ic + 0) * 9, IC, acc);
        mid_load(v0, ibase + (size_t)(ic + 4) * HW, off, msk);
        mid_fma<OCT>(v1, wbase + (size_t)(ic + 1) * 9, IC, acc);
        mid_load(v1, ibase + (size_t)(ic + 5) * HW, off, msk);
        mid_fma<OCT>(v2, wbase + (size_t)(ic + 2) * 9, IC, acc);
        mid_load(v2, ibase + (size_t)(ic + 6) * HW, off, msk);
        mid_fma<OCT>(v3, wbase + (size_t)(ic + 3) * 9, IC, acc);
        mid_load(v3, ibase + (size_t)(ic + 7) * HW, off, msk);
    }
    // tail: last 4 ics, no prefetch
    mid_fma<OCT>(v0, wbase + (size_t)(ic + 0) * 9, IC, acc);
    mid_fma<OCT>(v1, wbase + (size_t)(ic + 1) * 9, IC, acc);
    mid_fma<OCT>(v2, wbase + (size_t)(ic + 2) * 9, IC, acc);
    mid_fma<OCT>(v3, wbase + (size_t)(ic + 3) * 9, IC, acc);

    __shared__ float red[NW][OCT][64];
#pragma unroll
    for (int t = 0; t < OCT; ++t) red[wv][t][lane] = acc[t];
    __syncthreads();

    __shared__ float vals[OCT][64];
    float thr = thr_v[layer], leak = leak_v[layer];
    for (int s = tid; s < OCT * 64; s += NW * 64) {
        int t = s >> 6, p = s & 63;
        float sum = 0.f;
#pragma unroll
        for (int q = 0; q < NW; ++q) sum += red[q][t][p];
        size_t idx = (size_t)(b * OC + oc0 + t) * HW + ch * 64 + p;
        float mi = first ? 0.f : mem[idx];
        float mo;
        float val = lif_update(mi, sum, thr, leak, &mo);
        mem[idx] = mo;
        if (POOL) vals[t][p] = val;
        else out[idx] = val;
    }
    if (POOL) {
        __syncthreads();
        int Wo = W >> 1, Ho = H >> 1;
        for (int s = tid; s < OCT * 16; s += NW * 64) {
            int t = s >> 4, q = s & 15;
            int pr = q / Wo, pc = q % Wo;
            float pv = 0.25f * (vals[t][(2 * pr) * W + 2 * pc] +
                                vals[t][(2 * pr) * W + 2 * pc + 1] +
                                vals[t][(2 * pr + 1) * W + 2 * pc] +
                                vals[t][(2 * pr + 1) * W + 2 * pc + 1]);
            size_t pidx = ((size_t)(b * OC + oc0 + t) * Ho +
                           (ch * (rpw >> 1) + pr)) * Wo + pc;
            out[pidx] = pv;
        }
    }
}

// Layers 7-12 (4x4 / 2x2 planes). Block = 4 waves, one oc per block.
// ic = lane + 64*wv (+256*pass). Per-wave butterfly transpose-reduce;
// LDS [4][M] cross-wave reduce; parallel LIF; optional fused pool.
template <int S, int POOL>
__global__ void conv_small4_kernel(const float* __restrict__ in,
                                   const float* __restrict__ w,
                                   float* __restrict__ mem,
                                   float* __restrict__ out,
                                   const float* __restrict__ thr_v,
                                   const float* __restrict__ leak_v,
                                   int layer, int IC, int OC, int first) {
    constexpr int SS = S * S;
    constexpr int M = 4 * SS;              // 64 (S=4) or 16 (S=2)
    constexpr int LOG2M = (S == 4) ? 6 : 4;
    int tid = threadIdx.x;
    int lane = tid & 63;
    int wv = tid >> 6;  // 0..3
    int oc = blockIdx.x;

    float acc[M];
#pragma unroll
    for (int i = 0; i < M; ++i) acc[i] = 0.f;

    const float* wrow = w + (size_t)oc * IC * 9;
    for (int ic = lane + (wv << 6); ic < IC; ic += 256) {
        const float* wp = wrow + (size_t)ic * 9;
        float wvv[9];
#pragma unroll
        for (int k = 0; k < 9; ++k) wvv[k] = wp[k];
#pragma unroll
        for (int b = 0; b < 4; ++b) {
            const float4* ip = (const float4*)(in + (size_t)(b * IC + ic) * SS);
            float pv[SS];
#pragma unroll
            for (int q = 0; q < SS / 4; ++q) {
                float4 t4 = ip[q];
                pv[4 * q + 0] = t4.x;
                pv[4 * q + 1] = t4.y;
                pv[4 * q + 2] = t4.z;
                pv[4 * q + 3] = t4.w;
            }
#pragma unroll
            for (int y = 0; y < S; ++y)
#pragma unroll
                for (int x = 0; x < S; ++x) {
                    float a = acc[b * SS + y * S + x];
#pragma unroll
                    for (int ky = 0; ky < 3; ++ky) {
                        int yy = y + ky - 1;
                        if (yy < 0 || yy >= S) continue;
#pragma unroll
                        for (int kx = 0; kx < 3; ++kx) {
                            int xx = x + kx - 1;
                            if (xx < 0 || xx >= S) continue;
                            a = fmaf(pv[yy * S + xx], wvv[ky * 3 + kx], a);
                        }
                    }
                    acc[b * SS + y * S + x] = a;
                }
        }
    }

    // per-wave transpose-reduce: M accs across 64 lanes -> 1 value per lane
#pragma unroll
    for (int step = 0; step < LOG2M; ++step) {
        const int offx = 1 << step;
        const int half = M >> (step + 1);
        const bool hi = (lane & offx) != 0;
#pragma unroll
        for (int i = 0; i < half; ++i) {
            float sent = hi ? acc[i] : acc[i + half];
            float got = __shfl_xor(sent, offx);
            acc[i] = (hi ? acc[i + half] : acc[i]) + got;
        }
    }
    float sum = acc[0];
#pragma unroll
    for (int offx = M; offx < 64; offx <<= 1) sum += __shfl_xor(sum, offx);

    __shared__ float red[4][M];
    int o = (int)(__brev((unsigned)(lane & (M - 1))) >> (32 - LOG2M));
    if (lane < M) red[wv][o] = sum;
    __syncthreads();

    __shared__ float pvs[M];
    if (tid < M) {
        float tot = red[0][tid] + red[1][tid] + red[2][tid] + red[3][tid];
        int b = tid / SS, p = tid % SS;
        size_t idx = (size_t)(b * OC + oc) * SS + p;
        float mi = first ? 0.f : mem[idx];
        float mo;
        float val = lif_update(mi, tot, thr_v[layer], leak_v[layer], &mo);
        mem[idx] = mo;
        if (POOL) pvs[tid] = val;
        else out[idx] = val;
    }
    if (POOL) {
        __syncthreads();
        constexpr int Sh = S / 2, SSh = Sh * Sh;
        if (tid < 4 * SSh) {
            int b = tid / SSh, q = tid % SSh;
            int pr = q / Sh, pc = q % Sh;
            float pv = 0.25f * (pvs[b * SS + (2 * pr) * S + 2 * pc] +
                                pvs[b * SS + (2 * pr) * S + 2 * pc + 1] +
                                pvs[b * SS + (2 * pr + 1) * S + 2 * pc] +
                                pvs[b * SS + (2 * pr + 1) * S + 2 * pc + 1]);
            out[((size_t)(b * OC + oc) * Sh + pr) * Sh + pc] = pv;
        }
    }
}

// Wave-per-output-neuron FC+LIF (float4 K-split, 4-batch reuse).
__global__ void fc_lif_wave_kernel(const float* __restrict__ in,
                                   const float* __restrict__ w,
                                   float* __restrict__ mem,
                                   float* __restrict__ out,
                                   const float* __restrict__ thr_v,
                                   const float* __restrict__ leak_v,
                                   int layer, int Kd, int N, int first) {
    int wave = (blockIdx.x * blockDim.x + threadIdx.x) >> 6;
    int lane = threadIdx.x & 63;
    if (wave >= N) return;
    int j = wave;
    int K4 = Kd >> 2;
    const float4* wp = (const float4*)(w + (size_t)j * Kd);
    const float4* ip = (const float4*)in;
    float a0 = 0.f, a1 = 0.f, a2 = 0.f, a3 = 0.f;
    for (int k = lane; k < K4; k += 64) {
        float4 wv = wp[k];
        float4 v0 = ip[k];
        float4 v1 = ip[K4 + k];
        float4 v2 = ip[2 * K4 + k];
        float4 v3 = ip[3 * K4 + k];
        a0 = fmaf(wv.x, v0.x, fmaf(wv.y, v0.y, fmaf(wv.z, v0.z, fmaf(wv.w, v0.w, a0))));
        a1 = fmaf(wv.x, v1.x, fmaf(wv.y, v1.y, fmaf(wv.z, v1.z, fmaf(wv.w, v1.w, a1))));
        a2 = fmaf(wv.x, v2.x, fmaf(wv.y, v2.y, fmaf(wv.z, v2.z, fmaf(wv.w, v2.w, a2))));
        a3 = fmaf(wv.x, v3.x, fmaf(wv.y, v3.y, fmaf(wv.z, v3.z, fmaf(wv.w, v3.w, a3))));
    }
#pragma unroll
    for (int off = 32; off > 0; off >>= 1) {
        a0 += __shfl_xor(a0, off);
        a1 += __shfl_xor(a1, off);
        a2 += __shfl_xor(a2, off);
        a3 += __shfl_xor(a3, off);
    }
    if (lane == 0) {
        float thr = thr_v[layer], leak = leak_v[layer];
        float accv[4] = {a0, a1, a2, a3};
#pragma unroll
        for (int b = 0; b < BATCH; ++b) {
            float mi = first ? 0.f : mem[(size_t)b * N + j];
            float mo;
            float val = lif_update(mi, accv[b], thr, leak, &mo);
            mem[(size_t)b * N + j] = mo;
            out[(size_t)b * N + j] = val;
        }
    }
}

// One 64-thread block per (b, label). logits (+)= in[b,:] . w[l,:]
__global__ void fc2_acc_kernel(const float* __restrict__ in,
                               const float* __restrict__ w,
                               float* __restrict__ logits,
                               int Kd, int L, int init) {
    int o = blockIdx.x;
    int l = o % L;
    int b = o / L;
    int K4 = Kd >> 2;
    const float4* ip = (const float4*)(in + (size_t)b * Kd);
    const float4* wp = (const float4*)(w + (size_t)l * Kd);
    float s = 0.f;
    for (int k = threadIdx.x; k < K4; k += 64) {
        float4 iv = ip[k];
        float4 wv = wp[k];
        s = fmaf(iv.x, wv.x, fmaf(iv.y, wv.y, fmaf(iv.z, wv.z, fmaf(iv.w, wv.w, s))));
    }
#pragma unroll
    for (int off = 32; off > 0; off >>= 1) s += __shfl_xor(s, off);
    if (threadIdx.x == 0) logits[o] = init ? s : logits[o] + s;
}

extern "C" void kernel_launch(void* const* d_in, const int* in_sizes, int n_in,
                              void* d_out, int out_size, void* d_ws, size_t ws_size,
                              hipStream_t stream) {
    const float* x = (const float*)d_in[0];
    const float* convw[13];
    for (int i = 0; i < 13; ++i) convw[i] = (const float*)d_in[1 + i];
    const float* fc0 = (const float*)d_in[14];
    const float* fc1 = (const float*)d_in[15];
    const float* fc2 = (const float*)d_in[16];
    const float* thr = (const float*)d_in[17];
    const float* leak = (const float*)d_in[18];

    static const int IC[13] = {3, 64, 64, 128, 128, 256, 256, 256, 512, 512, 512, 512, 512};
    static const int OC[13] = {64, 64, 128, 128, 256, 256, 256, 512, 512, 512, 512, 512, 512};
    static const int HH[13] = {32, 32, 16, 16, 8, 8, 8, 4, 4, 4, 2, 2, 2};

    float* ws = (float*)d_ws;
    size_t off = 0;
    float* convmem[13];
    for (int i = 0; i < 13; ++i) {
        convmem[i] = ws + off;
        off += (size_t)BATCH * OC[i] * HH[i] * HH[i];
    }
    float* mfc0 = ws + off; off += BATCH * 4096;
    float* mfc1 = ws + off; off += BATCH * 4096;
    float* syn0 = ws + off; off += (size_t)BATCH * 64 * 32 * 32;  // L0 conv cache
    float* bufs[3];
    for (int i = 0; i < 3; ++i) { bufs[i] = ws + off; off += 262144; }

    for (int t = 0; t < 3; ++t) {
        int first = (t == 0);
        const float* src = x;
        int cur = -1;
        for (int i = 0; i < 13; ++i) {
            int d = (cur + 1) % 3;
            if (cur < 0) d = 0;
            int H = HH[i], W = HH[i];
            if (i == 0) {
                int n = BATCH * OC[i] * H * W;
                conv_lif_kernel<<<(n + 255) / 256, 256, 0, stream>>>(
                    src, convw[i], syn0, convmem[i], bufs[d], thr, leak, i,
                    IC[i], OC[i], H, W, n, first);
            } else if (i == 1) {
                // 64->64 @32x32, pool: OCT=8, NW=4 (icpw=16)
                int blocks = BATCH * (H * W / 64) * (OC[i] / 8);
                conv_mid_kernel<8, 4, 1><<<blocks, 256, 0, stream>>>(
                    src, convw[i], convmem[i], bufs[d], thr, leak, i,
                    IC[i], OC[i], H, W, first);
            } else if (i == 2) {
                // 64->128 @16x16: OCT=4, NW=4 (icpw=16)
                int blocks = BATCH * (H * W / 64) * (OC[i] / 4);
                conv_mid_kernel<4, 4, 0><<<blocks, 256, 0, stream>>>(
                    src, convw[i], convmem[i], bufs[d], thr, leak, i,
                    IC[i], OC[i], H, W, first);
            } else if (i == 3) {
                // 128->128 @16x16, pool: OCT=4, NW=8 (icpw=16)
                int blocks = BATCH * (H * W / 64) * (OC[i] / 4);
                conv_mid_kernel<4, 8, 1><<<blocks, 512, 0, stream>>>(
                    src, convw[i], convmem[i], bufs[d], thr, leak, i,
                    IC[i], OC[i], H, W, first);
            } else if (i == 4 || i == 5) {
                // @8x8: OCT=4, NW=8 (icpw=16/32)
                int blocks = BATCH * (H * W / 64) * (OC[i] / 4);
                conv_mid_kernel<4, 8, 0><<<blocks, 512, 0, stream>>>(
                    src, convw[i], convmem[i], bufs[d], thr, leak, i,
                    IC[i], OC[i], H, W, first);
            } else if (i == 6) {
                int blocks = BATCH * (H * W / 64) * (OC[i] / 4);
                conv_mid_kernel<4, 8, 1><<<blocks, 512, 0, stream>>>(
                    src, convw[i], convmem[i], bufs[d], thr, leak, i,
                    IC[i], OC[i], H, W, first);
            } else if (i == 7 || i == 8) {
                conv_small4_kernel<4, 0><<<OC[i], 256, 0, stream>>>(
                    src, convw[i], convmem[i], bufs[d], thr, leak, i,
                    IC[i], OC[i], first);
            } else if (i == 9) {
                conv_small4_kernel<4, 1><<<OC[i], 256, 0, stream>>>(
                    src, convw[i], convmem[i], bufs[d], thr, leak, i,
                    IC[i], OC[i], first);
            } else {  // 10..12, 2x2
                conv_small4_kernel<2, 0><<<OC[i], 256, 0, stream>>>(
                    src, convw[i], convmem[i], bufs[d], thr, leak, i,
                    IC[i], OC[i], first);
            }
            cur = d; src = bufs[cur];
        }
        {
            int d = (cur + 1) % 3;
            fc_lif_wave_kernel<<<(4096 * 64) / 256, 256, 0, stream>>>(
                src, fc0, mfc0, bufs[d], thr, leak, 13, 2048, 4096, first);
            cur = d; src = bufs[cur];
        }
        {
            int d = (cur + 1) % 3;
            fc_lif_wave_kernel<<<(4096 * 64) / 256, 256, 0, stream>>>(
                src, fc1, mfc1, bufs[d], thr, leak, 14, 4096, 4096, first);
            cur = d; src = bufs[cur];
        }
        fc2_acc_kernel<<<BATCH * 10, 64, 0, stream>>>(
            src, fc2, (float*)d_out, 4096, 10, first);
    }
}

// Round 4
// 899.171 us; speedup vs baseline: 3.3343x; 1.1985x over previous
//
#include <hip/hip_runtime.h>

// VGG16-A spiking NN, multi-compartment LIF (K=2), T=3, B=4, fp32.
// Round 10:
//  - Post-mortem r9: 4-deep pipeline cost 204 VGPR -> 2 waves/SIMD, 10%
//    occupancy; latency-bound loop got NO hiding. Counters (VALU 14%,
//    HBM 1.3%, occ 10%) say grid-starvation, not ILP shortage.
//  - Revert to 2-deep pipeline (VGPR ~90-130).
//  - More waves, less work each: L1 <8,4>->(4,8) 8192 waves; L2 ->4096;
//    L4-L6 OCT 4->2 (4096 waves); small4 L8-12 NW 4->8 (4096 waves).
//  - Kept: syn0 timestep-invariant L0 conv cache, fused avg-pool,
//    first-flag, no min-occupancy launch_bounds clause.

#define BATCH 4

__device__ __forceinline__ float lif_update(float mem_in, float syn, float thr,
                                            float leak, float* mem_out) {
    float m = leak * mem_in + syn;
    float val = 0.f;
    if ((m / thr - 1.f > 0.f) && (1.f - m / (2.f * thr) >= 0.f)) val += 1.f;
    if ((m / (2.f * thr) - 1.f > 0.f) && (1.f - m / (4.f * thr) >= 0.f)) val += 2.f;
    *mem_out = m - thr * val;
    return val;
}

// Element-per-thread conv+LIF (layer 0 only, IC=3). Conv result is
// timestep-invariant (analog input encoding): computed at t=0 into syn0,
// reloaded afterwards.
__global__ void conv_lif_kernel(const float* __restrict__ in,
                                const float* __restrict__ w,
                                float* __restrict__ syn0,
                                float* __restrict__ mem,
                                float* __restrict__ out,
                                const float* __restrict__ thr_v,
                                const float* __restrict__ leak_v,
                                int layer, int IC, int OC, int H, int W, int n,
                                int first) {
    int idx = blockIdx.x * blockDim.x + threadIdx.x;
    if (idx >= n) return;

    float syn;
    if (first) {
        int x  = idx % W;
        int y  = (idx / W) % H;
        int oc = (idx / (W * H)) % OC;
        int b  = idx / (W * H * OC);

        const float* wp = w + (size_t)oc * IC * 9;
        const float* ip = in + (size_t)b * IC * H * W;

        syn = 0.f;
        for (int ic = 0; ic < IC; ++ic) {
            const float* ipc = ip + (size_t)ic * H * W;
            const float* wpc = wp + ic * 9;
#pragma unroll
            for (int ky = 0; ky < 3; ++ky) {
                int yy = y + ky - 1;
                if (yy < 0 || yy >= H) continue;
#pragma unroll
                for (int kx = 0; kx < 3; ++kx) {
                    int xx = x + kx - 1;
                    if (xx < 0 || xx >= W) continue;
                    syn = fmaf(ipc[yy * W + xx], wpc[ky * 3 + kx], syn);
                }
            }
        }
        syn0[idx] = syn;
    } else {
        syn = syn0[idx];
    }
    float mi = first ? 0.f : mem[idx];
    float mo;
    float val = lif_update(mi, syn, thr_v[layer], leak_v[layer], &mo);
    mem[idx] = mo;
    out[idx] = val;
}

// ---- conv_mid helpers ----
__device__ __forceinline__ void mid_load(float v[9], const float* __restrict__ ip,
                                         const int off[9], const bool msk[9]) {
#pragma unroll
    for (int k = 0; k < 9; ++k) v[k] = msk[k] ? ip[off[k]] : 0.f;
}

template <int OCT>
__device__ __forceinline__ void mid_fma(const float v[9], const float* __restrict__ wp,
                                        int IC, float acc[OCT]) {
#pragma unroll
    for (int t = 0; t < OCT; ++t) {
        const float* wt = wp + (size_t)t * IC * 9;
#pragma unroll
        for (int k = 0; k < 9; ++k) acc[t] = fmaf(v[k], wt[k], acc[t]);
    }
}

// Layers 1-6. Block = NW waves. blockIdx -> (b, pixel-chunk, oc-group).
// Lane = pixel within 64-pixel chunk. Wave wv accumulates over its IC/NW
// channel chunk into acc[OCT] with a 2-deep pipeline (prefetch next ic);
// LDS reduce across waves; LIF; optional fused 2x2 avg-pool.
template <int OCT, int NW, int POOL>
__global__ __launch_bounds__(NW * 64)
void conv_mid_kernel(const float* __restrict__ in,
                     const float* __restrict__ w,
                     float* __restrict__ mem,
                     float* __restrict__ out,
                     const float* __restrict__ thr_v,
                     const float* __restrict__ leak_v,
                     int layer, int IC, int OC, int H, int W,
                     int first) {
    int tid = threadIdx.x;
    int lane = tid & 63;
    int wv = tid >> 6;  // 0..NW-1
    int ocg = OC / OCT;
    int HW = H * W;
    int chunks = HW >> 6;
    int bid = blockIdx.x;
    int g  = bid % ocg;
    int ch = (bid / ocg) % chunks;
    int b  = bid / (ocg * chunks);
    int rpw = 64 / W;
    int y = ch * rpw + lane / W;
    int x = lane % W;
    int oc0 = g * OCT;

    int off[9];
    bool msk[9];
#pragma unroll
    for (int ky = 0; ky < 3; ++ky)
#pragma unroll
        for (int kx = 0; kx < 3; ++kx) {
            int yy = y + ky - 1, xx = x + kx - 1;
            bool v = (yy >= 0 && yy < H && xx >= 0 && xx < W);
            msk[ky * 3 + kx] = v;
            off[ky * 3 + kx] = v ? yy * W + xx : 0;
        }

    float acc[OCT];
#pragma unroll
    for (int t = 0; t < OCT; ++t) acc[t] = 0.f;

    const float* ibase = in + (size_t)b * IC * HW;
    const float* wbase = w + (size_t)oc0 * IC * 9;

    int icpw = IC / NW;
    int ic0 = wv * icpw;
    int icend = ic0 + icpw;

    // 2-deep pipeline: v holds current ic's inputs, prefetch next into nv.
    float v[9];
    mid_load(v, ibase + (size_t)ic0 * HW, off, msk);
    for (int ic = ic0; ic < icend; ++ic) {
        int icn = (ic + 1 < icend) ? ic + 1 : ic;
        float nv[9];
        mid_load(nv, ibase + (size_t)icn * HW, off, msk);
        mid_fma<OCT>(v, wbase + (size_t)ic * 9, IC, acc);
#pragma unroll
        for (int k = 0; k < 9; ++k) v[k] = nv[k];
    }

    __shared__ float red[NW][OCT][64];
#pragma unroll
    for (int t = 0; t < OCT; ++t) red[wv][t][lane] = acc[t];
    __syncthreads();

    __shared__ float vals[OCT][64];
    float thr = thr_v[layer], leak = leak_v[layer];
    for (int s = tid; s < OCT * 64; s += NW * 64) {
        int t = s >> 6, p = s & 63;
        float sum = 0.f;
#pragma unroll
        for (int q = 0; q < NW; ++q) sum += red[q][t][p];
        size_t idx = (size_t)(b * OC + oc0 + t) * HW + ch * 64 + p;
        float mi = first ? 0.f : mem[idx];
        float mo;
        float val = lif_update(mi, sum, thr, leak, &mo);
        mem[idx] = mo;
        if (POOL) vals[t][p] = val;
        else out[idx] = val;
    }
    if (POOL) {
        __syncthreads();
        int Wo = W >> 1, Ho = H >> 1;
        for (int s = tid; s < OCT * 16; s += NW * 64) {
            int t = s >> 4, q = s & 15;
            int pr = q / Wo, pc = q % Wo;
            float pv = 0.25f * (vals[t][(2 * pr) * W + 2 * pc] +
                                vals[t][(2 * pr) * W + 2 * pc + 1] +
                                vals[t][(2 * pr + 1) * W + 2 * pc] +
                                vals[t][(2 * pr + 1) * W + 2 * pc + 1]);
            size_t pidx = ((size_t)(b * OC + oc0 + t) * Ho +
                           (ch * (rpw >> 1) + pr)) * Wo + pc;
            out[pidx] = pv;
        }
    }
}

// Layers 7-12 (4x4 / 2x2 planes). Block = NW waves, one oc per block.
// ic = lane + 64*wv (+64*NW*pass). Per-wave butterfly transpose-reduce;
// LDS [NW][M] cross-wave reduce; parallel LIF; optional fused pool.
template <int S, int NW, int POOL>
__global__ __launch_bounds__(NW * 64)
void conv_small4_kernel(const float* __restrict__ in,
                        const float* __restrict__ w,
                        float* __restrict__ mem,
                        float* __restrict__ out,
                        const float* __restrict__ thr_v,
                        const float* __restrict__ leak_v,
                        int layer, int IC, int OC, int first) {
    constexpr int SS = S * S;
    constexpr int M = 4 * SS;              // 64 (S=4) or 16 (S=2)
    constexpr int LOG2M = (S == 4) ? 6 : 4;
    int tid = threadIdx.x;
    int lane = tid & 63;
    int wv = tid >> 6;  // 0..NW-1
    int oc = blockIdx.x;

    float acc[M];
#pragma unroll
    for (int i = 0; i < M; ++i) acc[i] = 0.f;

    const float* wrow = w + (size_t)oc * IC * 9;
    for (int ic = lane + (wv << 6); ic < IC; ic += NW * 64) {
        const float* wp = wrow + (size_t)ic * 9;
        float wvv[9];
#pragma unroll
        for (int k = 0; k < 9; ++k) wvv[k] = wp[k];
#pragma unroll
        for (int b = 0; b < 4; ++b) {
            const float4* ip = (const float4*)(in + (size_t)(b * IC + ic) * SS);
            float pv[SS];
#pragma unroll
            for (int q = 0; q < SS / 4; ++q) {
                float4 t4 = ip[q];
                pv[4 * q + 0] = t4.x;
                pv[4 * q + 1] = t4.y;
                pv[4 * q + 2] = t4.z;
                pv[4 * q + 3] = t4.w;
            }
#pragma unroll
            for (int y = 0; y < S; ++y)
#pragma unroll
                for (int x = 0; x < S; ++x) {
                    float a = acc[b * SS + y * S + x];
#pragma unroll
                    for (int ky = 0; ky < 3; ++ky) {
                        int yy = y + ky - 1;
                        if (yy < 0 || yy >= S) continue;
#pragma unroll
                        for (int kx = 0; kx < 3; ++kx) {
                            int xx = x + kx - 1;
                            if (xx < 0 || xx >= S) continue;
                            a = fmaf(pv[yy * S + xx], wvv[ky * 3 + kx], a);
                        }
                    }
                    acc[b * SS + y * S + x] = a;
                }
        }
    }

    // per-wave transpose-reduce: M accs across 64 lanes -> 1 value per lane
#pragma unroll
    for (int step = 0; step < LOG2M; ++step) {
        const int offx = 1 << step;
        const int half = M >> (step + 1);
        const bool hi = (lane & offx) != 0;
#pragma unroll
        for (int i = 0; i < half; ++i) {
            float sent = hi ? acc[i] : acc[i + half];
            float got = __shfl_xor(sent, offx);
            acc[i] = (hi ? acc[i + half] : acc[i]) + got;
        }
    }
    float sum = acc[0];
#pragma unroll
    for (int offx = M; offx < 64; offx <<= 1) sum += __shfl_xor(sum, offx);

    __shared__ float red[NW][M];
    int o = (int)(__brev((unsigned)(lane & (M - 1))) >> (32 - LOG2M));
    if (lane < M) red[wv][o] = sum;
    __syncthreads();

    __shared__ float pvs[M];
    if (tid < M) {
        float tot = 0.f;
#pragma unroll
        for (int q = 0; q < NW; ++q) tot += red[q][tid];
        int b = tid / SS, p = tid % SS;
        size_t idx = (size_t)(b * OC + oc) * SS + p;
        float mi = first ? 0.f : mem[idx];
        float mo;
        float val = lif_update(mi, tot, thr_v[layer], leak_v[layer], &mo);
        mem[idx] = mo;
        if (POOL) pvs[tid] = val;
        else out[idx] = val;
    }
    if (POOL) {
        __syncthreads();
        constexpr int Sh = S / 2, SSh = Sh * Sh;
        if (tid < 4 * SSh) {
            int b = tid / SSh, q = tid % SSh;
            int pr = q / Sh, pc = q % Sh;
            float pv = 0.25f * (pvs[b * SS + (2 * pr) * S + 2 * pc] +
                                pvs[b * SS + (2 * pr) * S + 2 * pc + 1] +
                                pvs[b * SS + (2 * pr + 1) * S + 2 * pc] +
                                pvs[b * SS + (2 * pr + 1) * S + 2 * pc + 1]);
            out[((size_t)(b * OC + oc) * Sh + pr) * Sh + pc] = pv;
        }
    }
}

// Wave-per-output-neuron FC+LIF (float4 K-split, 4-batch reuse).
__global__ void fc_lif_wave_kernel(const float* __restrict__ in,
                                   const float* __restrict__ w,
                                   float* __restrict__ mem,
                                   float* __restrict__ out,
                                   const float* __restrict__ thr_v,
                                   const float* __restrict__ leak_v,
                                   int layer, int Kd, int N, int first) {
    int wave = (blockIdx.x * blockDim.x + threadIdx.x) >> 6;
    int lane = threadIdx.x & 63;
    if (wave >= N) return;
    int j = wave;
    int K4 = Kd >> 2;
    const float4* wp = (const float4*)(w + (size_t)j * Kd);
    const float4* ip = (const float4*)in;
    float a0 = 0.f, a1 = 0.f, a2 = 0.f, a3 = 0.f;
    for (int k = lane; k < K4; k += 64) {
        float4 wv = wp[k];
        float4 v0 = ip[k];
        float4 v1 = ip[K4 + k];
        float4 v2 = ip[2 * K4 + k];
        float4 v3 = ip[3 * K4 + k];
        a0 = fmaf(wv.x, v0.x, fmaf(wv.y, v0.y, fmaf(wv.z, v0.z, fmaf(wv.w, v0.w, a0))));
        a1 = fmaf(wv.x, v1.x, fmaf(wv.y, v1.y, fmaf(wv.z, v1.z, fmaf(wv.w, v1.w, a1))));
        a2 = fmaf(wv.x, v2.x, fmaf(wv.y, v2.y, fmaf(wv.z, v2.z, fmaf(wv.w, v2.w, a2))));
        a3 = fmaf(wv.x, v3.x, fmaf(wv.y, v3.y, fmaf(wv.z, v3.z, fmaf(wv.w, v3.w, a3))));
    }
#pragma unroll
    for (int off = 32; off > 0; off >>= 1) {
        a0 += __shfl_xor(a0, off);
        a1 += __shfl_xor(a1, off);
        a2 += __shfl_xor(a2, off);
        a3 += __shfl_xor(a3, off);
    }
    if (lane == 0) {
        float thr = thr_v[layer], leak = leak_v[layer];
        float accv[4] = {a0, a1, a2, a3};
#pragma unroll
        for (int b = 0; b < BATCH; ++b) {
            float mi = first ? 0.f : mem[(size_t)b * N + j];
            float mo;
            float val = lif_update(mi, accv[b], thr, leak, &mo);
            mem[(size_t)b * N + j] = mo;
            out[(size_t)b * N + j] = val;
        }
    }
}

// One 64-thread block per (b, label). logits (+)= in[b,:] . w[l,:]
__global__ void fc2_acc_kernel(const float* __restrict__ in,
                               const float* __restrict__ w,
                               float* __restrict__ logits,
                               int Kd, int L, int init) {
    int o = blockIdx.x;
    int l = o % L;
    int b = o / L;
    int K4 = Kd >> 2;
    const float4* ip = (const float4*)(in + (size_t)b * Kd);
    const float4* wp = (const float4*)(w + (size_t)l * Kd);
    float s = 0.f;
    for (int k = threadIdx.x; k < K4; k += 64) {
        float4 iv = ip[k];
        float4 wv = wp[k];
        s = fmaf(iv.x, wv.x, fmaf(iv.y, wv.y, fmaf(iv.z, wv.z, fmaf(iv.w, wv.w, s))));
    }
#pragma unroll
    for (int off = 32; off > 0; off >>= 1) s += __shfl_xor(s, off);
    if (threadIdx.x == 0) logits[o] = init ? s : logits[o] + s;
}

extern "C" void kernel_launch(void* const* d_in, const int* in_sizes, int n_in,
                              void* d_out, int out_size, void* d_ws, size_t ws_size,
                              hipStream_t stream) {
    const float* x = (const float*)d_in[0];
    const float* convw[13];
    for (int i = 0; i < 13; ++i) convw[i] = (const float*)d_in[1 + i];
    const float* fc0 = (const float*)d_in[14];
    const float* fc1 = (const float*)d_in[15];
    const float* fc2 = (const float*)d_in[16];
    const float* thr = (const float*)d_in[17];
    const float* leak = (const float*)d_in[18];

    static const int IC[13] = {3, 64, 64, 128, 128, 256, 256, 256, 512, 512, 512, 512, 512};
    static const int OC[13] = {64, 64, 128, 128, 256, 256, 256, 512, 512, 512, 512, 512, 512};
    static const int HH[13] = {32, 32, 16, 16, 8, 8, 8, 4, 4, 4, 2, 2, 2};

    float* ws = (float*)d_ws;
    size_t off = 0;
    float* convmem[13];
    for (int i = 0; i < 13; ++i) {
        convmem[i] = ws + off;
        off += (size_t)BATCH * OC[i] * HH[i] * HH[i];
    }
    float* mfc0 = ws + off; off += BATCH * 4096;
    float* mfc1 = ws + off; off += BATCH * 4096;
    float* syn0 = ws + off; off += (size_t)BATCH * 64 * 32 * 32;  // L0 conv cache
    float* bufs[3];
    for (int i = 0; i < 3; ++i) { bufs[i] = ws + off; off += 262144; }

    for (int t = 0; t < 3; ++t) {
        int first = (t == 0);
        const float* src = x;
        int cur = -1;
        for (int i = 0; i < 13; ++i) {
            int d = (cur + 1) % 3;
            if (cur < 0) d = 0;
            int H = HH[i], W = HH[i];
            if (i == 0) {
                int n = BATCH * OC[i] * H * W;
                conv_lif_kernel<<<(n + 255) / 256, 256, 0, stream>>>(
                    src, convw[i], syn0, convmem[i], bufs[d], thr, leak, i,
                    IC[i], OC[i], H, W, n, first);
            } else if (i == 1) {
                // 64->64 @32x32, pool: OCT=4, NW=8 -> 1024 blk x 8w = 8192 waves
                int blocks = BATCH * (H * W / 64) * (OC[i] / 4);
                conv_mid_kernel<4, 8, 1><<<blocks, 512, 0, stream>>>(
                    src, convw[i], convmem[i], bufs[d], thr, leak, i,
                    IC[i], OC[i], H, W, first);
            } else if (i == 2) {
                // 64->128 @16x16: OCT=4, NW=8 -> 512 blk x 8w = 4096 waves
                int blocks = BATCH * (H * W / 64) * (OC[i] / 4);
                conv_mid_kernel<4, 8, 0><<<blocks, 512, 0, stream>>>(
                    src, convw[i], convmem[i], bufs[d], thr, leak, i,
                    IC[i], OC[i], H, W, first);
            } else if (i == 3) {
                // 128->128 @16x16, pool: OCT=4, NW=8 -> 4096 waves
                int blocks = BATCH * (H * W / 64) * (OC[i] / 4);
                conv_mid_kernel<4, 8, 1><<<blocks, 512, 0, stream>>>(
                    src, convw[i], convmem[i], bufs[d], thr, leak, i,
                    IC[i], OC[i], H, W, first);
            } else if (i == 4 || i == 5) {
                // @8x8: OCT=2, NW=8 -> 512 blk x 8w = 4096 waves
                int blocks = BATCH * (H * W / 64) * (OC[i] / 2);
                conv_mid_kernel<2, 8, 0><<<blocks, 512, 0, stream>>>(
                    src, convw[i], convmem[i], bufs[d], thr, leak, i,
                    IC[i], OC[i], H, W, first);
            } else if (i == 6) {
                int blocks = BATCH * (H * W / 64) * (OC[i] / 2);
                conv_mid_kernel<2, 8, 1><<<blocks, 512, 0, stream>>>(
                    src, convw[i], convmem[i], bufs[d], thr, leak, i,
                    IC[i], OC[i], H, W, first);
            } else if (i == 7) {
                // IC=256: NW=4 (waves 4..7 would idle at NW=8)
                conv_small4_kernel<4, 4, 0><<<OC[i], 256, 0, stream>>>(
                    src, convw[i], convmem[i], bufs[d], thr, leak, i,
                    IC[i], OC[i], first);
            } else if (i == 8) {
                // IC=512: NW=8, each wave covers exactly 64 ics
                conv_small4_kernel<4, 8, 0><<<OC[i], 512, 0, stream>>>(
                    src, convw[i], convmem[i], bufs[d], thr, leak, i,
                    IC[i], OC[i], first);
            } else if (i == 9) {
                conv_small4_kernel<4, 8, 1><<<OC[i], 512, 0, stream>>>(
                    src, convw[i], convmem[i], bufs[d], thr, leak, i,
                    IC[i], OC[i], first);
            } else {  // 10..12, 2x2, IC=512
                conv_small4_kernel<2, 8, 0><<<OC[i], 512, 0, stream>>>(
                    src, convw[i], convmem[i], bufs[d], thr, leak, i,
                    IC[i], OC[i], first);
            }
            cur = d; src = bufs[cur];
        }
        {
            int d = (cur + 1) % 3;
            fc_lif_wave_kernel<<<(4096 * 64) / 256, 256, 0, stream>>>(
                src, fc0, mfc0, bufs[d], thr, leak, 13, 2048, 4096, first);
            cur = d; src = bufs[cur];
        }
        {
            int d = (cur + 1) % 3;
            fc_lif_wave_kernel<<<(4096 * 64) / 256, 256, 0, stream>>>(
                src, fc1, mfc1, bufs[d], thr, leak, 14, 4096, 4096, first);
            cur = d; src = bufs[cur];
        }
        fc2_acc_kernel<<<BATCH * 10, 64, 0, stream>>>(
            src, fc2, (float*)d_out, 4096, 10, first);
    }
}

// Round 5
// 671.673 us; speedup vs baseline: 4.4636x; 1.3387x over previous
//
#include <hip/hip_runtime.h>

// VGG16-A spiking NN, multi-compartment LIF (K=2), T=3, B=4, fp32.
// Round 11: LAYER-OUTER / TIMESTEP-INNER restructure.
//  - Analog input encoding => layer i's 3 timestep outputs depend only on
//    layer i-1's 3 outputs + private membrane chain. Each layer = ONE
//    kernel computing t=0,1,2 with membrane carried in REGISTERS.
//  - 48 dispatches -> 16. convmem/mfc workspace traffic gone. FC weights
//    read once (was 3x). conv_mid interleaves 3 independent timestep
//    convs -> 3x ILP without extra pipeline registers (r7/r9 lesson:
//    VGPR<=~130, no min-occupancy launch_bounds clause).
//  - small4 (acc[64]) runs timesteps sequentially in-kernel: gains the
//    fusion + in-register membranes without tripling acc registers.

#define BATCH 4

__device__ __forceinline__ float lif_update(float mem_in, float syn, float thr,
                                            float leak, float* mem_out) {
    float m = leak * mem_in + syn;
    float val = 0.f;
    if ((m / thr - 1.f > 0.f) && (1.f - m / (2.f * thr) >= 0.f)) val += 1.f;
    if ((m / (2.f * thr) - 1.f > 0.f) && (1.f - m / (4.f * thr) >= 0.f)) val += 2.f;
    *mem_out = m - thr * val;
    return val;
}

// Layer 0: conv(x,w0) computed once (timestep-invariant), 3 LIF steps in
// registers, 3 spike outputs. One dispatch for the whole layer.
__global__ void conv_lif0_kernel(const float* __restrict__ in,
                                 const float* __restrict__ w,
                                 float* __restrict__ out0,
                                 float* __restrict__ out1,
                                 float* __restrict__ out2,
                                 const float* __restrict__ thr_v,
                                 const float* __restrict__ leak_v,
                                 int IC, int OC, int H, int W, int n) {
    int idx = blockIdx.x * blockDim.x + threadIdx.x;
    if (idx >= n) return;
    int x  = idx % W;
    int y  = (idx / W) % H;
    int oc = (idx / (W * H)) % OC;
    int b  = idx / (W * H * OC);

    const float* wp = w + (size_t)oc * IC * 9;
    const float* ip = in + (size_t)b * IC * H * W;

    float syn = 0.f;
    for (int ic = 0; ic < IC; ++ic) {
        const float* ipc = ip + (size_t)ic * H * W;
        const float* wpc = wp + ic * 9;
#pragma unroll
        for (int ky = 0; ky < 3; ++ky) {
            int yy = y + ky - 1;
            if (yy < 0 || yy >= H) continue;
#pragma unroll
            for (int kx = 0; kx < 3; ++kx) {
                int xx = x + kx - 1;
                if (xx < 0 || xx >= W) continue;
                syn = fmaf(ipc[yy * W + xx], wpc[ky * 3 + kx], syn);
            }
        }
    }
    float thr = thr_v[0], leak = leak_v[0];
    float m = 0.f;
    float v0 = lif_update(m, syn, thr, leak, &m);
    float v1 = lif_update(m, syn, thr, leak, &m);
    float v2 = lif_update(m, syn, thr, leak, &m);
    out0[idx] = v0;
    out1[idx] = v1;
    out2[idx] = v2;
}

// ---- conv_mid helpers ----
__device__ __forceinline__ void mid_load(float v[9], const float* __restrict__ ip,
                                         const int off[9], const bool msk[9]) {
#pragma unroll
    for (int k = 0; k < 9; ++k) v[k] = msk[k] ? ip[off[k]] : 0.f;
}

template <int OCT>
__device__ __forceinline__ void mid_fma(const float v[9], const float* __restrict__ wp,
                                        int IC, float acc[OCT]) {
#pragma unroll
    for (int t = 0; t < OCT; ++t) {
        const float* wt = wp + (size_t)t * IC * 9;
#pragma unroll
        for (int k = 0; k < 9; ++k) acc[t] = fmaf(v[k], wt[k], acc[t]);
    }
}

// Layers 1-6, all 3 timesteps fused. Block = NW waves. blockIdx ->
// (b, pixel-chunk, oc-group). Wave wv covers its IC/NW channel chunk for
// ALL 3 timesteps (independent conv streams -> 27 loads + 3*OCT*9 FMAs
// per ic = built-in ILP). LDS reduce + in-register membrane chain + LIF
// per timestep; optional fused 2x2 avg-pool. Requires OCT <= NW.
template <int OCT, int NW, int POOL>
__global__ __launch_bounds__(NW * 64)
void conv_mid3_kernel(const float* __restrict__ in0,
                      const float* __restrict__ in1,
                      const float* __restrict__ in2,
                      const float* __restrict__ w,
                      float* __restrict__ out0,
                      float* __restrict__ out1,
                      float* __restrict__ out2,
                      const float* __restrict__ thr_v,
                      const float* __restrict__ leak_v,
                      int layer, int IC, int OC, int H, int W) {
    int tid = threadIdx.x;
    int lane = tid & 63;
    int wv = tid >> 6;  // 0..NW-1
    int ocg = OC / OCT;
    int HW = H * W;
    int chunks = HW >> 6;
    int bid = blockIdx.x;
    int g  = bid % ocg;
    int ch = (bid / ocg) % chunks;
    int b  = bid / (ocg * chunks);
    int rpw = 64 / W;
    int y = ch * rpw + lane / W;
    int x = lane % W;
    int oc0 = g * OCT;

    int off[9];
    bool msk[9];
#pragma unroll
    for (int ky = 0; ky < 3; ++ky)
#pragma unroll
        for (int kx = 0; kx < 3; ++kx) {
            int yy = y + ky - 1, xx = x + kx - 1;
            bool v = (yy >= 0 && yy < H && xx >= 0 && xx < W);
            msk[ky * 3 + kx] = v;
            off[ky * 3 + kx] = v ? yy * W + xx : 0;
        }

    size_t boff = (size_t)b * IC * HW;
    const float* ib[3] = {in0 + boff, in1 + boff, in2 + boff};
    float* const outs[3] = {out0, out1, out2};
    const float* wbase = w + (size_t)oc0 * IC * 9;

    float acc[3][OCT];
#pragma unroll
    for (int t = 0; t < 3; ++t)
#pragma unroll
        for (int q = 0; q < OCT; ++q) acc[t][q] = 0.f;

    int icpw = IC / NW;
    int ic0 = wv * icpw;
    int icend = ic0 + icpw;

    float vc[3][9];
#pragma unroll
    for (int t = 0; t < 3; ++t) mid_load(vc[t], ib[t] + (size_t)ic0 * HW, off, msk);

    for (int ic = ic0; ic < icend; ++ic) {
        int icn = (ic + 1 < icend) ? ic + 1 : ic;
        const float* wp = wbase + (size_t)ic * 9;
        float nv[3][9];
#pragma unroll
        for (int t = 0; t < 3; ++t) {
            mid_load(nv[t], ib[t] + (size_t)icn * HW, off, msk);
            mid_fma<OCT>(vc[t], wp, IC, acc[t]);
        }
#pragma unroll
        for (int t = 0; t < 3; ++t)
#pragma unroll
            for (int k = 0; k < 9; ++k) vc[t][k] = nv[t][k];
    }

    __shared__ float red[NW][OCT][64];
    __shared__ float vals[OCT][64];
    float thr = thr_v[layer], leak = leak_v[layer];
    float mem_reg = 0.f;  // membrane carried in-register across timesteps
    int eq = tid >> 6, ep = tid & 63;  // epilogue element (tid < OCT*64)
    int Wo = W >> 1, Ho = H >> 1;

#pragma unroll
    for (int t = 0; t < 3; ++t) {
        __syncthreads();  // protect red/vals from previous timestep's readers
#pragma unroll
        for (int q = 0; q < OCT; ++q) red[wv][q][lane] = acc[t][q];
        __syncthreads();
        if (tid < OCT * 64) {
            float sum = 0.f;
#pragma unroll
            for (int q = 0; q < NW; ++q) sum += red[q][eq][ep];
            float val = lif_update(mem_reg, sum, thr, leak, &mem_reg);
            if (POOL) {
                vals[eq][ep] = val;
            } else {
                size_t idx = (size_t)(b * OC + oc0 + eq) * HW + ch * 64 + ep;
                outs[t][idx] = val;
            }
        }
        if (POOL) {
            __syncthreads();
            if (tid < OCT * 16) {
                int q = tid >> 4, s = tid & 15;
                int pr = s / Wo, pc = s % Wo;
                float pv = 0.25f * (vals[q][(2 * pr) * W + 2 * pc] +
                                    vals[q][(2 * pr) * W + 2 * pc + 1] +
                                    vals[q][(2 * pr + 1) * W + 2 * pc] +
                                    vals[q][(2 * pr + 1) * W + 2 * pc + 1]);
                size_t pidx = ((size_t)(b * OC + oc0 + q) * Ho +
                               (ch * (rpw >> 1) + pr)) * Wo + pc;
                outs[t][pidx] = pv;
            }
        }
    }
}

// Layers 7-12 (4x4 / 2x2 planes), 3 timesteps fused (sequential passes,
// membrane in-register). Block = NW waves, one oc per block.
template <int S, int NW, int POOL>
__global__ __launch_bounds__(NW * 64)
void conv_small4_3_kernel(const float* __restrict__ in0,
                          const float* __restrict__ in1,
                          const float* __restrict__ in2,
                          const float* __restrict__ w,
                          float* __restrict__ out0,
                          float* __restrict__ out1,
                          float* __restrict__ out2,
                          const float* __restrict__ thr_v,
                          const float* __restrict__ leak_v,
                          int layer, int IC, int OC) {
    constexpr int SS = S * S;
    constexpr int M = 4 * SS;              // 64 (S=4) or 16 (S=2)
    constexpr int LOG2M = (S == 4) ? 6 : 4;
    int tid = threadIdx.x;
    int lane = tid & 63;
    int wv = tid >> 6;  // 0..NW-1
    int oc = blockIdx.x;

    const float* const ins[3] = {in0, in1, in2};
    float* const outs[3] = {out0, out1, out2};
    const float* wrow = w + (size_t)oc * IC * 9;

    __shared__ float red[NW][M];
    __shared__ float pvs[M];
    float thr = thr_v[layer], leak = leak_v[layer];
    float mem_reg = 0.f;  // for tid < M

#pragma unroll
    for (int t = 0; t < 3; ++t) {
        const float* inb = ins[t];
        float acc[M];
#pragma unroll
        for (int i = 0; i < M; ++i) acc[i] = 0.f;

        for (int ic = lane + (wv << 6); ic < IC; ic += NW * 64) {
            const float* wp = wrow + (size_t)ic * 9;
            float wvv[9];
#pragma unroll
            for (int k = 0; k < 9; ++k) wvv[k] = wp[k];
#pragma unroll
            for (int b = 0; b < 4; ++b) {
                const float4* ip = (const float4*)(inb + (size_t)(b * IC + ic) * SS);
                float pv[SS];
#pragma unroll
                for (int q = 0; q < SS / 4; ++q) {
                    float4 t4 = ip[q];
                    pv[4 * q + 0] = t4.x;
                    pv[4 * q + 1] = t4.y;
                    pv[4 * q + 2] = t4.z;
                    pv[4 * q + 3] = t4.w;
                }
#pragma unroll
                for (int y = 0; y < S; ++y)
#pragma unroll
                    for (int x = 0; x < S; ++x) {
                        float a = acc[b * SS + y * S + x];
#pragma unroll
                        for (int ky = 0; ky < 3; ++ky) {
                            int yy = y + ky - 1;
                            if (yy < 0 || yy >= S) continue;
#pragma unroll
                            for (int kx = 0; kx < 3; ++kx) {
                                int xx = x + kx - 1;
                                if (xx < 0 || xx >= S) continue;
                                a = fmaf(pv[yy * S + xx], wvv[ky * 3 + kx], a);
                            }
                        }
                        acc[b * SS + y * S + x] = a;
                    }
            }
        }

        // per-wave transpose-reduce: M accs across 64 lanes -> 1 per lane
#pragma unroll
        for (int step = 0; step < LOG2M; ++step) {
            const int offx = 1 << step;
            const int half = M >> (step + 1);
            const bool hi = (lane & offx) != 0;
#pragma unroll
            for (int i = 0; i < half; ++i) {
                float sent = hi ? acc[i] : acc[i + half];
                float got = __shfl_xor(sent, offx);
                acc[i] = (hi ? acc[i + half] : acc[i]) + got;
            }
        }
        float sum = acc[0];
#pragma unroll
        for (int offx = M; offx < 64; offx <<= 1) sum += __shfl_xor(sum, offx);

        __syncthreads();  // protect red/pvs from previous timestep's readers
        int o = (int)(__brev((unsigned)(lane & (M - 1))) >> (32 - LOG2M));
        if (lane < M) red[wv][o] = sum;
        __syncthreads();

        if (tid < M) {
            float tot = 0.f;
#pragma unroll
            for (int q = 0; q < NW; ++q) tot += red[q][tid];
            int b = tid / SS, p = tid % SS;
            float val = lif_update(mem_reg, tot, thr, leak, &mem_reg);
            if (POOL) {
                pvs[tid] = val;
            } else {
                size_t idx = (size_t)(b * OC + oc) * SS + p;
                outs[t][idx] = val;
            }
        }
        if (POOL) {
            __syncthreads();
            constexpr int Sh = S / 2, SSh = Sh * Sh;
            if (tid < 4 * SSh) {
                int b = tid / SSh, q = tid % SSh;
                int pr = q / Sh, pc = q % Sh;
                float pv = 0.25f * (pvs[b * SS + (2 * pr) * S + 2 * pc] +
                                    pvs[b * SS + (2 * pr) * S + 2 * pc + 1] +
                                    pvs[b * SS + (2 * pr + 1) * S + 2 * pc] +
                                    pvs[b * SS + (2 * pr + 1) * S + 2 * pc + 1]);
                outs[t][((size_t)(b * OC + oc) * Sh + pr) * Sh + pc] = pv;
            }
        }
    }
}

// Wave-per-output-neuron FC+LIF, 3 timesteps fused: weight row read ONCE,
// 12 accumulators (3t x 4b), membrane chain at lane 0.
__global__ void fc_lif3_kernel(const float* __restrict__ in0,
                               const float* __restrict__ in1,
                               const float* __restrict__ in2,
                               const float* __restrict__ w,
                               float* __restrict__ out0,
                               float* __restrict__ out1,
                               float* __restrict__ out2,
                               const float* __restrict__ thr_v,
                               const float* __restrict__ leak_v,
                               int layer, int Kd, int N) {
    int wave = (blockIdx.x * blockDim.x + threadIdx.x) >> 6;
    int lane = threadIdx.x & 63;
    if (wave >= N) return;
    int j = wave;
    int K4 = Kd >> 2;
    const float4* wp = (const float4*)(w + (size_t)j * Kd);
    const float4* ip[3] = {(const float4*)in0, (const float4*)in1, (const float4*)in2};
    float* const outs[3] = {out0, out1, out2};

    float a[3][4];
#pragma unroll
    for (int t = 0; t < 3; ++t)
#pragma unroll
        for (int b = 0; b < 4; ++b) a[t][b] = 0.f;

    for (int k = lane; k < K4; k += 64) {
        float4 wv = wp[k];
#pragma unroll
        for (int t = 0; t < 3; ++t)
#pragma unroll
            for (int b = 0; b < 4; ++b) {
                float4 v = ip[t][b * K4 + k];
                a[t][b] = fmaf(wv.x, v.x, fmaf(wv.y, v.y,
                          fmaf(wv.z, v.z, fmaf(wv.w, v.w, a[t][b]))));
            }
    }
#pragma unroll
    for (int t = 0; t < 3; ++t)
#pragma unroll
        for (int b = 0; b < 4; ++b)
#pragma unroll
            for (int off = 32; off > 0; off >>= 1)
                a[t][b] += __shfl_xor(a[t][b], off);

    if (lane == 0) {
        float thr = thr_v[layer], leak = leak_v[layer];
#pragma unroll
        for (int b = 0; b < BATCH; ++b) {
            float m = 0.f;
#pragma unroll
            for (int t = 0; t < 3; ++t) {
                float val = lif_update(m, a[t][b], thr, leak, &m);
                outs[t][(size_t)b * N + j] = val;
            }
        }
    }
}

// One 64-thread block per (b, label). logits = sum_t in_t[b,:] . w[l,:]
__global__ void fc2_acc3_kernel(const float* __restrict__ in0,
                                const float* __restrict__ in1,
                                const float* __restrict__ in2,
                                const float* __restrict__ w,
                                float* __restrict__ logits,
                                int Kd, int L) {
    int o = blockIdx.x;
    int l = o % L;
    int b = o / L;
    int K4 = Kd >> 2;
    const float4* ip[3] = {(const float4*)(in0 + (size_t)b * Kd),
                           (const float4*)(in1 + (size_t)b * Kd),
                           (const float4*)(in2 + (size_t)b * Kd)};
    const float4* wp = (const float4*)(w + (size_t)l * Kd);
    float st[3] = {0.f, 0.f, 0.f};
    for (int k = threadIdx.x; k < K4; k += 64) {
        float4 wv = wp[k];
#pragma unroll
        for (int t = 0; t < 3; ++t) {
            float4 iv = ip[t][k];
            st[t] = fmaf(iv.x, wv.x, fmaf(iv.y, wv.y,
                    fmaf(iv.z, wv.z, fmaf(iv.w, wv.w, st[t]))));
        }
    }
#pragma unroll
    for (int t = 0; t < 3; ++t)
#pragma unroll
        for (int off = 32; off > 0; off >>= 1) st[t] += __shfl_xor(st[t], off);
    if (threadIdx.x == 0) logits[o] = (st[0] + st[1]) + st[2];
}

extern "C" void kernel_launch(void* const* d_in, const int* in_sizes, int n_in,
                              void* d_out, int out_size, void* d_ws, size_t ws_size,
                              hipStream_t stream) {
    const float* x = (const float*)d_in[0];
    const float* convw[13];
    for (int i = 0; i < 13; ++i) convw[i] = (const float*)d_in[1 + i];
    const float* fc0 = (const float*)d_in[14];
    const float* fc1 = (const float*)d_in[15];
    const float* fc2 = (const float*)d_in[16];
    const float* thr = (const float*)d_in[17];
    const float* leak = (const float*)d_in[18];

    static const int IC[13] = {3, 64, 64, 128, 128, 256, 256, 256, 512, 512, 512, 512, 512};
    static const int OC[13] = {64, 64, 128, 128, 256, 256, 256, 512, 512, 512, 512, 512, 512};
    static const int HH[13] = {32, 32, 16, 16, 8, 8, 8, 4, 4, 4, 2, 2, 2};

    float* ws = (float*)d_ws;
    // two ping-pong sets of 3 timestep buffers, 262144 floats each
    float* A[3];
    float* B[3];
    size_t off = 0;
    for (int i = 0; i < 3; ++i) { A[i] = ws + off; off += 262144; }
    for (int i = 0; i < 3; ++i) { B[i] = ws + off; off += 262144; }

    // L0: conv once + 3 in-register LIF steps -> A
    {
        int n = BATCH * 64 * 32 * 32;
        conv_lif0_kernel<<<(n + 255) / 256, 256, 0, stream>>>(
            x, convw[0], A[0], A[1], A[2], thr, leak, 3, 64, 32, 32, n);
    }

    float** src = A;
    float** dst = B;

    // L1-L6: conv_mid3
    for (int i = 1; i <= 6; ++i) {
        int H = HH[i], W = HH[i];
        int blocks;
        if (i <= 3) {
            blocks = BATCH * (H * W / 64) * (OC[i] / 4);
            if (i == 1)
                conv_mid3_kernel<4, 8, 1><<<blocks, 512, 0, stream>>>(
                    src[0], src[1], src[2], convw[i], dst[0], dst[1], dst[2],
                    thr, leak, i, IC[i], OC[i], H, W);
            else if (i == 2)
                conv_mid3_kernel<4, 8, 0><<<blocks, 512, 0, stream>>>(
                    src[0], src[1], src[2], convw[i], dst[0], dst[1], dst[2],
                    thr, leak, i, IC[i], OC[i], H, W);
            else
                conv_mid3_kernel<4, 8, 1><<<blocks, 512, 0, stream>>>(
                    src[0], src[1], src[2], convw[i], dst[0], dst[1], dst[2],
                    thr, leak, i, IC[i], OC[i], H, W);
        } else {
            blocks = BATCH * (H * W / 64) * (OC[i] / 2);
            if (i == 6)
                conv_mid3_kernel<2, 8, 1><<<blocks, 512, 0, stream>>>(
                    src[0], src[1], src[2], convw[i], dst[0], dst[1], dst[2],
                    thr, leak, i, IC[i], OC[i], H, W);
            else
                conv_mid3_kernel<2, 8, 0><<<blocks, 512, 0, stream>>>(
                    src[0], src[1], src[2], convw[i], dst[0], dst[1], dst[2],
                    thr, leak, i, IC[i], OC[i], H, W);
        }
        float** tmp = src; src = dst; dst = tmp;
    }

    // L7-L12: conv_small4_3
    for (int i = 7; i <= 12; ++i) {
        if (i == 7)
            conv_small4_3_kernel<4, 4, 0><<<OC[i], 256, 0, stream>>>(
                src[0], src[1], src[2], convw[i], dst[0], dst[1], dst[2],
                thr, leak, i, IC[i], OC[i]);
        else if (i == 8)
            conv_small4_3_kernel<4, 8, 0><<<OC[i], 512, 0, stream>>>(
                src[0], src[1], src[2], convw[i], dst[0], dst[1], dst[2],
                thr, leak, i, IC[i], OC[i]);
        else if (i == 9)
            conv_small4_3_kernel<4, 8, 1><<<OC[i], 512, 0, stream>>>(
                src[0], src[1], src[2], convw[i], dst[0], dst[1], dst[2],
                thr, leak, i, IC[i], OC[i]);
        else
            conv_small4_3_kernel<2, 8, 0><<<OC[i], 512, 0, stream>>>(
                src[0], src[1], src[2], convw[i], dst[0], dst[1], dst[2],
                thr, leak, i, IC[i], OC[i]);
        float** tmp = src; src = dst; dst = tmp;
    }

    // fc0, fc1 (LIF), fc2 (logit accumulate over t)
    fc_lif3_kernel<<<(4096 * 64) / 256, 256, 0, stream>>>(
        src[0], src[1], src[2], fc0, dst[0], dst[1], dst[2],
        thr, leak, 13, 2048, 4096);
    { float** tmp = src; src = dst; dst = tmp; }

    fc_lif3_kernel<<<(4096 * 64) / 256, 256, 0, stream>>>(
        src[0], src[1], src[2], fc1, dst[0], dst[1], dst[2],
        thr, leak, 14, 4096, 4096);
    { float** tmp = src; src = dst; dst = tmp; }

    fc2_acc3_kernel<<<BATCH * 10, 64, 0, stream>>>(
        src[0], src[1], src[2], fc2, (float*)d_out, 4096, 10);
}